// Round 2
// baseline (3920.111 us; speedup 1.0000x reference)
//
#include <hip/hip_runtime.h>
#include <math.h>

// Problem constants (fixed by the reference)
#define NB   8
#define SL   2048
#define DM   512
#define DI   1024
#define NDS  64
#define DTR  32
#define NROWS (NB*SL)   // 16384

#define BM 128
#define BN 64
#define BK 16

__device__ __forceinline__ float sigmoidf_(float x){ return 1.0f/(1.0f + __expf(-x)); }

// ---------------- fallback: zero the output (ws too small diagnostic) -------
__global__ void __launch_bounds__(256) zero_kernel(float* __restrict__ p, int n)
{
  const int i = blockIdx.x*256 + threadIdx.x;
  if (i < n) p[i] = 0.0f;
}

// ---------------- LayerNorm: one wave per row ----------------
__global__ void __launch_bounds__(256) ln_kernel(const float* __restrict__ x,
    const float* __restrict__ w, const float* __restrict__ b, float* __restrict__ out)
{
  const int wave = threadIdx.x >> 6;
  const int lane = threadIdx.x & 63;
  const int row  = (blockIdx.x << 2) + wave;
  const float* xr = x + (size_t)row * DM;
  float4 v0 = *(const float4*)(xr + lane*4);
  float4 v1 = *(const float4*)(xr + 256 + lane*4);
  float s = v0.x+v0.y+v0.z+v0.w + v1.x+v1.y+v1.z+v1.w;
  float q = v0.x*v0.x+v0.y*v0.y+v0.z*v0.z+v0.w*v0.w
          + v1.x*v1.x+v1.y*v1.y+v1.z*v1.z+v1.w*v1.w;
  #pragma unroll
  for (int off=1; off<64; off<<=1){ s += __shfl_xor(s, off); q += __shfl_xor(q, off); }
  const float mean = s * (1.0f/DM);
  const float var  = q * (1.0f/DM) - mean*mean;
  const float rstd = rsqrtf(var + 1e-5f);
  float4 w0 = *(const float4*)(w + lane*4);
  float4 w1 = *(const float4*)(w + 256 + lane*4);
  float4 b0 = *(const float4*)(b + lane*4);
  float4 b1 = *(const float4*)(b + 256 + lane*4);
  float* orow = out + (size_t)row * DM;
  float4 o0, o1;
  o0.x = (v0.x-mean)*rstd*w0.x + b0.x;
  o0.y = (v0.y-mean)*rstd*w0.y + b0.y;
  o0.z = (v0.z-mean)*rstd*w0.z + b0.z;
  o0.w = (v0.w-mean)*rstd*w0.w + b0.w;
  o1.x = (v1.x-mean)*rstd*w1.x + b1.x;
  o1.y = (v1.y-mean)*rstd*w1.y + b1.y;
  o1.z = (v1.z-mean)*rstd*w1.z + b1.z;
  o1.w = (v1.w-mean)*rstd*w1.w + b1.w;
  *(float4*)(orow + lane*4)       = o0;
  *(float4*)(orow + 256 + lane*4) = o1;
}

// ---------------- Generic GEMM: C[M,N] = A[M,K] * W[N,K]^T (+res) ----------------
__global__ void __launch_bounds__(256) gemm_bt(const float* __restrict__ A,
    const float* __restrict__ W, float* __restrict__ C, const float* __restrict__ res,
    int M, int N, int K)
{
  __shared__ __align__(16) float As[BK][BM];
  __shared__ __align__(16) float Ws[BK][BN];
  const int t  = threadIdx.x;
  const int tx = t & 15, ty = t >> 4;
  const int m0 = blockIdx.y * BM;
  const int n0 = blockIdx.x * BN;
  const int rowA = t >> 2;          // 0..63
  const int colA = (t & 3) << 2;    // 0,4,8,12

  float acc[8][4];
  #pragma unroll
  for (int i=0;i<8;i++)
    #pragma unroll
    for (int j=0;j<4;j++) acc[i][j]=0.f;

  for (int k0 = 0; k0 < K; k0 += BK) {
    // stage A tile 128x16 (transposed into [k][m])
    #pragma unroll
    for (int i=0;i<2;i++){
      const int m = m0 + rowA + i*64;
      const float4 v = *(const float4*)(A + (size_t)m*K + k0 + colA);
      As[colA+0][rowA+i*64]=v.x; As[colA+1][rowA+i*64]=v.y;
      As[colA+2][rowA+i*64]=v.z; As[colA+3][rowA+i*64]=v.w;
    }
    // stage W tile 64x16
    {
      const int n = n0 + rowA;
      float4 v = make_float4(0.f,0.f,0.f,0.f);
      if (n < N) v = *(const float4*)(W + (size_t)n*K + k0 + colA);
      Ws[colA+0][rowA]=v.x; Ws[colA+1][rowA]=v.y;
      Ws[colA+2][rowA]=v.z; Ws[colA+3][rowA]=v.w;
    }
    __syncthreads();
    #pragma unroll
    for (int kk=0; kk<BK; kk++){
      const float4 a0 = *(const float4*)(&As[kk][ty*8]);
      const float4 a1 = *(const float4*)(&As[kk][ty*8+4]);
      const float4 bv = *(const float4*)(&Ws[kk][tx*4]);
      const float av[8] = {a0.x,a0.y,a0.z,a0.w,a1.x,a1.y,a1.z,a1.w};
      const float bw[4] = {bv.x,bv.y,bv.z,bv.w};
      #pragma unroll
      for (int i=0;i<8;i++)
        #pragma unroll
        for (int j=0;j<4;j++)
          acc[i][j] += av[i]*bw[j];
    }
    __syncthreads();
  }
  const int n = n0 + (tx<<2);
  if (n < N) {
    #pragma unroll
    for (int i=0;i<8;i++){
      const int m = m0 + ty*8 + i;
      float4 o;
      o.x=acc[i][0]; o.y=acc[i][1]; o.z=acc[i][2]; o.w=acc[i][3];
      if (res) {
        const float4 r = *(const float4*)(res + (size_t)m*N + n);
        o.x+=r.x; o.y+=r.y; o.z+=r.z; o.w+=r.w;
      }
      *(float4*)(C + (size_t)m*N + n) = o;
    }
  }
}

// ---------------- Causal depthwise conv (width 4) + SiLU ----------------
// input u_raw has stride DI now
__global__ void __launch_bounds__(256) conv_silu_kernel(const float* __restrict__ u_raw,
    const float* __restrict__ cw, const float* __restrict__ cb, float* __restrict__ uc)
{
  const int gid = blockIdx.x*256 + threadIdx.x;     // 0 .. NROWS*DI-1
  const int d   = gid & (DI-1);
  const int row = gid >> 10;
  const int l   = row & (SL-1);
  float acc = cb[d];
  const float* w = cw + d*4;
  #pragma unroll
  for (int k=0;k<4;k++){
    const int ll = l-3+k;
    if (ll >= 0) acc += u_raw[(size_t)(row-3+k)*DI + d] * w[k];
  }
  uc[gid] = acc * sigmoidf_(acc);
}

// ---------------- dt = softplus(dt_part @ dtp_w^T + b) ----------------
// block: 256 threads; grid (row_groups=NROWS/64, d_groups=DI/256)
__global__ void __launch_bounds__(256) dt_kernel(const float* __restrict__ xdbl,
    const float* __restrict__ w, const float* __restrict__ bias, float* __restrict__ dt_out)
{
  const int d     = blockIdx.y*256 + threadIdx.x;
  const int rbase = blockIdx.x*64;
  float wr[32];
  #pragma unroll
  for (int i=0;i<8;i++){
    const float4 v = *(const float4*)(w + (size_t)d*DTR + i*4);
    wr[i*4+0]=v.x; wr[i*4+1]=v.y; wr[i*4+2]=v.z; wr[i*4+3]=v.w;
  }
  const float bb = bias[d];
  __shared__ __align__(16) float xd[64][32];
  #pragma unroll
  for (int ii=0; ii<2; ii++){
    const int i  = threadIdx.x + ii*256;   // 0..511 float4 slots
    const int rl = i >> 3, qo = (i & 7) << 2;
    const float4 v = *(const float4*)(xdbl + (size_t)(rbase+rl)*160 + qo);
    *(float4*)&xd[rl][qo] = v;
  }
  __syncthreads();
  for (int rl=0; rl<64; rl++){
    float acc = bb;
    #pragma unroll
    for (int r=0;r<DTR;r++) acc += xd[rl][r]*wr[r];
    const float sp = (acc > 20.0f) ? acc : logf(1.0f + __expf(acc));
    dt_out[(size_t)(rbase+rl)*DI + d] = sp;
  }
}

// ---------------- Selective scan (+ D skip + SiLU(z) gate) ----------------
// wave = (batch, 4 d-channels); lane: dl = lane>>4 (which d), sg = lane&15
// each lane holds 4 states s = sg*4+j. Reduce over sg via 4 shfl_xor steps.
// NOTE: yg may alias dt_s (y written in-place over dt after its last use) —
// no __restrict__ on those two. Within a wave the prefetch loads of step l+1
// issue before the sg==0 store of y[l] (program order, lockstep), so in-place
// overwrite is safe.
__global__ void __launch_bounds__(256) scan_kernel(
    const float* dt_s, const float* __restrict__ uc,
    const float* __restrict__ zb, const float* __restrict__ xdbl,
    const float* __restrict__ A_log, const float* __restrict__ Dv,
    float* yg)
{
  const int wave  = threadIdx.x >> 6;
  const int lane  = threadIdx.x & 63;
  const int batch = blockIdx.x >> 6;
  const int dbase = ((blockIdx.x & 63) << 4) + (wave << 2);
  const int dl = lane >> 4, sg = lane & 15;
  const int d  = dbase + dl;

  const float a0 = -__expf(A_log[(size_t)d*NDS + sg*4 + 0]);
  const float a1 = -__expf(A_log[(size_t)d*NDS + sg*4 + 1]);
  const float a2 = -__expf(A_log[(size_t)d*NDS + sg*4 + 2]);
  const float a3 = -__expf(A_log[(size_t)d*NDS + sg*4 + 3]);
  float h0=0.f,h1=0.f,h2=0.f,h3=0.f;
  const float Dval = Dv[d];

  const size_t r0 = (size_t)batch * SL;
  const float* dtp = dt_s + r0*DI + d;
  const float* up  = uc   + r0*DI + d;
  const float* zp  = zb   + r0*DI + d;
  const float* bp  = xdbl + r0*160 + 32 + (sg<<2);
  const float* cp  = xdbl + r0*160 + 96 + (sg<<2);
  float*       yp  = yg   + r0*DI + d;

  float dt = dtp[0], u = up[0], z = zp[0];
  float4 Bv = *(const float4*)bp;
  float4 Cv = *(const float4*)cp;

  for (int l = 0; l < SL; ++l) {
    // software prefetch of step l+1 (hide L2 latency at 2 waves/SIMD)
    float dt_n=0.f, u_n=0.f, z_n=0.f;
    float4 B_n = make_float4(0.f,0.f,0.f,0.f), C_n = B_n;
    if (l+1 < SL) {
      dt_n = dtp[(size_t)(l+1)*DI];
      u_n  = up [(size_t)(l+1)*DI];
      z_n  = zp [(size_t)(l+1)*DI];
      B_n  = *(const float4*)(bp + (size_t)(l+1)*160);
      C_n  = *(const float4*)(cp + (size_t)(l+1)*160);
    }
    const float dtu = dt*u;
    h0 = __expf(dt*a0)*h0 + dtu*Bv.x;
    h1 = __expf(dt*a1)*h1 + dtu*Bv.y;
    h2 = __expf(dt*a2)*h2 + dtu*Bv.z;
    h3 = __expf(dt*a3)*h3 + dtu*Bv.w;
    float p = h0*Cv.x + h1*Cv.y + h2*Cv.z + h3*Cv.w;
    p += __shfl_xor(p,1); p += __shfl_xor(p,2);
    p += __shfl_xor(p,4); p += __shfl_xor(p,8);
    if (sg == 0) {
      const float y = p + u*Dval;
      yp[(size_t)l*DI] = y * z * sigmoidf_(z);
    }
    dt=dt_n; u=u_n; z=z_n; Bv=B_n; Cv=C_n;
  }
}

extern "C" void kernel_launch(void* const* d_in, const int* in_sizes, int n_in,
                              void* d_out, int out_size, void* d_ws, size_t ws_size,
                              hipStream_t stream)
{
  const float* x      = (const float*)d_in[0];
  const float* ln_w   = (const float*)d_in[1];
  const float* ln_b   = (const float*)d_in[2];
  const float* inpw   = (const float*)d_in[3];
  const float* convw  = (const float*)d_in[4];
  const float* convb  = (const float*)d_in[5];
  const float* xpw    = (const float*)d_in[6];
  const float* dtpw   = (const float*)d_in[7];
  const float* dtpb   = (const float*)d_in[8];
  const float* A_log  = (const float*)d_in[9];
  const float* Dmat   = (const float*)d_in[10];
  const float* outw   = (const float*)d_in[11];
  float* out = (float*)d_out;

  // Compact workspace layout with liveness-based aliasing (floats):
  //  R1 [8.4M]  : hln (ln -> in_proj), then xdb (x_proj -> scan)
  //  R2 [16.8M] : u_raw (in_proj -> conv), then dtb (dt -> scan),
  //               then y written in-place over dtb by scan (-> out_proj)
  //  R3 [16.8M] : zbuf (in_proj -> scan)
  //  R4 [16.8M] : ucb  (conv -> scan)
  // total = 58,720,256 floats = 224 MiB
  const size_t R1 = (size_t)NROWS * DM;          // 8,388,608
  const size_t RB = (size_t)NROWS * DI;          // 16,777,216
  const size_t need = (R1 + 3*RB) * sizeof(float);
  if (ws_size < need) {
    // diagnostic fallback: clean absmax failure instead of an OOB crash
    zero_kernel<<<(out_size+255)/256, 256, 0, stream>>>(out, out_size);
    return;
  }
  float* buf   = (float*)d_ws;
  float* hln   = buf;                 // R1
  float* xdb   = buf;                 // R1 (after hln dies)
  float* u_raw = buf + R1;            // R2
  float* dtb   = buf + R1;            // R2 (after u_raw dies); y in-place
  float* zbuf  = buf + R1 + RB;       // R3
  float* ucb   = buf + R1 + 2*RB;     // R4

  for (int l = 0; l < 2; ++l) {
    const float* xin = (l == 0) ? x : out;
    ln_kernel<<<NROWS/4, 256, 0, stream>>>(xin, ln_w + l*DM, ln_b + l*DM, hln);
    // in_proj split: u half and z half, each [NROWS x DI], K=DM
    gemm_bt<<<dim3(DI/BN, NROWS/BM), 256, 0, stream>>>(
        hln, inpw + (size_t)l*2*DI*DM, u_raw, nullptr, NROWS, DI, DM);
    gemm_bt<<<dim3(DI/BN, NROWS/BM), 256, 0, stream>>>(
        hln, inpw + (size_t)l*2*DI*DM + (size_t)DI*DM, zbuf, nullptr, NROWS, DI, DM);
    conv_silu_kernel<<<(NROWS*DI)/256, 256, 0, stream>>>(
        u_raw, convw + l*DI*4, convb + l*DI, ucb);
    gemm_bt<<<dim3((160+BN-1)/BN, NROWS/BM), 256, 0, stream>>>(
        ucb, xpw + (size_t)l*160*DI, xdb, nullptr, NROWS, 160, DI);
    dt_kernel<<<dim3(NROWS/64, DI/256), 256, 0, stream>>>(
        xdb, dtpw + (size_t)l*DI*DTR, dtpb + l*DI, dtb);
    scan_kernel<<<NB*64, 256, 0, stream>>>(
        dtb, ucb, zbuf, xdb, A_log + (size_t)l*DI*NDS, Dmat + l*DI, dtb /* y in-place */);
    gemm_bt<<<dim3(DM/BN, NROWS/BM), 256, 0, stream>>>(
        dtb, outw + (size_t)l*DM*DI, out, xin, NROWS, DM, DI);
  }
}

// Round 3
// 3183.451 us; speedup vs baseline: 1.2314x; 1.2314x over previous
//
#include <hip/hip_runtime.h>
#include <math.h>

// Problem constants (fixed by the reference)
#define NB   8
#define SL   2048
#define DM   512
#define DI   1024
#define NDS  64
#define DTR  32
#define NROWS (NB*SL)   // 16384

#define BM 128
#define BN 64
#define BK 16

#define TCH 8   // scan time-chunk (register-resident, double-buffered)

__device__ __forceinline__ float sigmoidf_(float x){ return 1.0f/(1.0f + __expf(-x)); }

// ---------------- fallback: zero the output (ws too small diagnostic) -------
__global__ void __launch_bounds__(256) zero_kernel(float* __restrict__ p, int n)
{
  const int i = blockIdx.x*256 + threadIdx.x;
  if (i < n) p[i] = 0.0f;
}

// ---------------- LayerNorm: one wave per row ----------------
__global__ void __launch_bounds__(256) ln_kernel(const float* __restrict__ x,
    const float* __restrict__ w, const float* __restrict__ b, float* __restrict__ out)
{
  const int wave = threadIdx.x >> 6;
  const int lane = threadIdx.x & 63;
  const int row  = (blockIdx.x << 2) + wave;
  const float* xr = x + (size_t)row * DM;
  float4 v0 = *(const float4*)(xr + lane*4);
  float4 v1 = *(const float4*)(xr + 256 + lane*4);
  float s = v0.x+v0.y+v0.z+v0.w + v1.x+v1.y+v1.z+v1.w;
  float q = v0.x*v0.x+v0.y*v0.y+v0.z*v0.z+v0.w*v0.w
          + v1.x*v1.x+v1.y*v1.y+v1.z*v1.z+v1.w*v1.w;
  #pragma unroll
  for (int off=1; off<64; off<<=1){ s += __shfl_xor(s, off); q += __shfl_xor(q, off); }
  const float mean = s * (1.0f/DM);
  const float var  = q * (1.0f/DM) - mean*mean;
  const float rstd = rsqrtf(var + 1e-5f);
  float4 w0 = *(const float4*)(w + lane*4);
  float4 w1 = *(const float4*)(w + 256 + lane*4);
  float4 b0 = *(const float4*)(b + lane*4);
  float4 b1 = *(const float4*)(b + 256 + lane*4);
  float* orow = out + (size_t)row * DM;
  float4 o0, o1;
  o0.x = (v0.x-mean)*rstd*w0.x + b0.x;
  o0.y = (v0.y-mean)*rstd*w0.y + b0.y;
  o0.z = (v0.z-mean)*rstd*w0.z + b0.z;
  o0.w = (v0.w-mean)*rstd*w0.w + b0.w;
  o1.x = (v1.x-mean)*rstd*w1.x + b1.x;
  o1.y = (v1.y-mean)*rstd*w1.y + b1.y;
  o1.z = (v1.z-mean)*rstd*w1.z + b1.z;
  o1.w = (v1.w-mean)*rstd*w1.w + b1.w;
  *(float4*)(orow + lane*4)       = o0;
  *(float4*)(orow + 256 + lane*4) = o1;
}

// ---------------- Generic GEMM: C[M,N] = A[M,K] * W[N,K]^T (+res) ----------------
__global__ void __launch_bounds__(256) gemm_bt(const float* __restrict__ A,
    const float* __restrict__ W, float* __restrict__ C, const float* __restrict__ res,
    int M, int N, int K)
{
  __shared__ __align__(16) float As[BK][BM];
  __shared__ __align__(16) float Ws[BK][BN];
  const int t  = threadIdx.x;
  const int tx = t & 15, ty = t >> 4;
  const int m0 = blockIdx.y * BM;
  const int n0 = blockIdx.x * BN;
  const int rowA = t >> 2;          // 0..63
  const int colA = (t & 3) << 2;    // 0,4,8,12

  float acc[8][4];
  #pragma unroll
  for (int i=0;i<8;i++)
    #pragma unroll
    for (int j=0;j<4;j++) acc[i][j]=0.f;

  for (int k0 = 0; k0 < K; k0 += BK) {
    // stage A tile 128x16 (transposed into [k][m])
    #pragma unroll
    for (int i=0;i<2;i++){
      const int m = m0 + rowA + i*64;
      const float4 v = *(const float4*)(A + (size_t)m*K + k0 + colA);
      As[colA+0][rowA+i*64]=v.x; As[colA+1][rowA+i*64]=v.y;
      As[colA+2][rowA+i*64]=v.z; As[colA+3][rowA+i*64]=v.w;
    }
    // stage W tile 64x16
    {
      const int n = n0 + rowA;
      float4 v = make_float4(0.f,0.f,0.f,0.f);
      if (n < N) v = *(const float4*)(W + (size_t)n*K + k0 + colA);
      Ws[colA+0][rowA]=v.x; Ws[colA+1][rowA]=v.y;
      Ws[colA+2][rowA]=v.z; Ws[colA+3][rowA]=v.w;
    }
    __syncthreads();
    #pragma unroll
    for (int kk=0; kk<BK; kk++){
      const float4 a0 = *(const float4*)(&As[kk][ty*8]);
      const float4 a1 = *(const float4*)(&As[kk][ty*8+4]);
      const float4 bv = *(const float4*)(&Ws[kk][tx*4]);
      const float av[8] = {a0.x,a0.y,a0.z,a0.w,a1.x,a1.y,a1.z,a1.w};
      const float bw[4] = {bv.x,bv.y,bv.z,bv.w};
      #pragma unroll
      for (int i=0;i<8;i++)
        #pragma unroll
        for (int j=0;j<4;j++)
          acc[i][j] += av[i]*bw[j];
    }
    __syncthreads();
  }
  const int n = n0 + (tx<<2);
  if (n < N) {
    #pragma unroll
    for (int i=0;i<8;i++){
      const int m = m0 + ty*8 + i;
      float4 o;
      o.x=acc[i][0]; o.y=acc[i][1]; o.z=acc[i][2]; o.w=acc[i][3];
      if (res) {
        const float4 r = *(const float4*)(res + (size_t)m*N + n);
        o.x+=r.x; o.y+=r.y; o.z+=r.z; o.w+=r.w;
      }
      *(float4*)(C + (size_t)m*N + n) = o;
    }
  }
}

// ---------------- Causal depthwise conv (width 4) + SiLU ----------------
__global__ void __launch_bounds__(256) conv_silu_kernel(const float* __restrict__ u_raw,
    const float* __restrict__ cw, const float* __restrict__ cb, float* __restrict__ uc)
{
  const int gid = blockIdx.x*256 + threadIdx.x;     // 0 .. NROWS*DI-1
  const int d   = gid & (DI-1);
  const int row = gid >> 10;
  const int l   = row & (SL-1);
  float acc = cb[d];
  const float* w = cw + d*4;
  #pragma unroll
  for (int k=0;k<4;k++){
    const int ll = l-3+k;
    if (ll >= 0) acc += u_raw[(size_t)(row-3+k)*DI + d] * w[k];
  }
  uc[gid] = acc * sigmoidf_(acc);
}

// ---------------- dt = softplus(dt_part @ dtp_w^T + b) ----------------
__global__ void __launch_bounds__(256) dt_kernel(const float* __restrict__ xdbl,
    const float* __restrict__ w, const float* __restrict__ bias, float* __restrict__ dt_out)
{
  const int d     = blockIdx.y*256 + threadIdx.x;
  const int rbase = blockIdx.x*64;
  float wr[32];
  #pragma unroll
  for (int i=0;i<8;i++){
    const float4 v = *(const float4*)(w + (size_t)d*DTR + i*4);
    wr[i*4+0]=v.x; wr[i*4+1]=v.y; wr[i*4+2]=v.z; wr[i*4+3]=v.w;
  }
  const float bb = bias[d];
  __shared__ __align__(16) float xd[64][32];
  #pragma unroll
  for (int ii=0; ii<2; ii++){
    const int i  = threadIdx.x + ii*256;   // 0..511 float4 slots
    const int rl = i >> 3, qo = (i & 7) << 2;
    const float4 v = *(const float4*)(xdbl + (size_t)(rbase+rl)*160 + qo);
    *(float4*)&xd[rl][qo] = v;
  }
  __syncthreads();
  for (int rl=0; rl<64; rl++){
    float acc = bb;
    #pragma unroll
    for (int r=0;r<DTR;r++) acc += xd[rl][r]*wr[r];
    const float sp = (acc > 20.0f) ? acc : logf(1.0f + __expf(acc));
    dt_out[(size_t)(rbase+rl)*DI + d] = sp;
  }
}

// ---------------- Selective scan (+ D skip + SiLU(z) gate) ----------------
// wave = (batch, 4 d-channels); lane: dl = lane>>4 (which d), sg = lane&15
// each lane holds 4 states s = sg*4+j. Reduce over sg via 4 shfl_xor steps.
// Time is processed in register-resident chunks of TCH steps with two
// buffers: chunk c+1's ~40 loads are all in flight while chunk c computes
// from registers (memory-level parallelism; the round-2 profile showed the
// 1-step prefetch version was HBM-latency-bound at 1190 cyc/step).
// NOTE: yg aliases dt_s (y written in-place over dt). Safe: chunk-(c+1)
// loads are issued before chunk-c stores (program order) and all inter-chunk
// address ranges are disjoint; no two waves share elements.
struct ScanStep { float dt, u, z; float4 B, C; };

__device__ __forceinline__ void scan_load_chunk(ScanStep s[TCH],
    const float* dtp, const float* up, const float* zp,
    const float* bp, const float* cp, int base)
{
  #pragma unroll
  for (int t=0; t<TCH; t++){
    const size_t o  = (size_t)(base+t)*DI;
    const size_t o2 = (size_t)(base+t)*160;
    s[t].dt = dtp[o];
    s[t].u  = up [o];
    s[t].z  = zp [o];
    s[t].B  = *(const float4*)(bp + o2);
    s[t].C  = *(const float4*)(cp + o2);
  }
}

__global__ void __launch_bounds__(256, 2) scan_kernel(
    const float* dt_s, const float* __restrict__ uc,
    const float* __restrict__ zb, const float* __restrict__ xdbl,
    const float* __restrict__ A_log, const float* __restrict__ Dv,
    float* yg)
{
  const int wave  = threadIdx.x >> 6;
  const int lane  = threadIdx.x & 63;
  const int batch = blockIdx.x >> 6;
  const int dbase = ((blockIdx.x & 63) << 4) + (wave << 2);
  const int dl = lane >> 4, sg = lane & 15;
  const int d  = dbase + dl;

  const float a0 = -__expf(A_log[(size_t)d*NDS + sg*4 + 0]);
  const float a1 = -__expf(A_log[(size_t)d*NDS + sg*4 + 1]);
  const float a2 = -__expf(A_log[(size_t)d*NDS + sg*4 + 2]);
  const float a3 = -__expf(A_log[(size_t)d*NDS + sg*4 + 3]);
  float h0=0.f,h1=0.f,h2=0.f,h3=0.f;
  const float Dval = Dv[d];

  const size_t r0 = (size_t)batch * SL;
  const float* dtp = dt_s + r0*DI + d;
  const float* up  = uc   + r0*DI + d;
  const float* zp  = zb   + r0*DI + d;
  const float* bp  = xdbl + r0*160 + 32 + (sg<<2);
  const float* cp  = xdbl + r0*160 + 96 + (sg<<2);
  float*       yp  = yg   + r0*DI + d;

  ScanStep buf0[TCH], buf1[TCH];
  scan_load_chunk(buf0, dtp, up, zp, bp, cp, 0);

  for (int base = 0; base < SL; base += 2*TCH) {
    // prefetch chunk base+TCH into buf1 (always valid: base <= SL-2*TCH)
    scan_load_chunk(buf1, dtp, up, zp, bp, cp, base + TCH);
    // compute chunk at `base` from buf0
    #pragma unroll
    for (int t=0; t<TCH; t++){
      const ScanStep& s = buf0[t];
      const float dtu = s.dt * s.u;
      h0 = __expf(s.dt*a0)*h0 + dtu*s.B.x;
      h1 = __expf(s.dt*a1)*h1 + dtu*s.B.y;
      h2 = __expf(s.dt*a2)*h2 + dtu*s.B.z;
      h3 = __expf(s.dt*a3)*h3 + dtu*s.B.w;
      float p = h0*s.C.x + h1*s.C.y + h2*s.C.z + h3*s.C.w;
      p += __shfl_xor(p,1); p += __shfl_xor(p,2);
      p += __shfl_xor(p,4); p += __shfl_xor(p,8);
      if (sg == 0) {
        const float y = p + s.u*Dval;
        yp[(size_t)(base+t)*DI] = y * s.z * sigmoidf_(s.z);
      }
    }
    // prefetch chunk base+2*TCH into buf0 (skip on last iteration)
    if (base + 2*TCH < SL)
      scan_load_chunk(buf0, dtp, up, zp, bp, cp, base + 2*TCH);
    // compute chunk at base+TCH from buf1
    #pragma unroll
    for (int t=0; t<TCH; t++){
      const ScanStep& s = buf1[t];
      const float dtu = s.dt * s.u;
      h0 = __expf(s.dt*a0)*h0 + dtu*s.B.x;
      h1 = __expf(s.dt*a1)*h1 + dtu*s.B.y;
      h2 = __expf(s.dt*a2)*h2 + dtu*s.B.z;
      h3 = __expf(s.dt*a3)*h3 + dtu*s.B.w;
      float p = h0*s.C.x + h1*s.C.y + h2*s.C.z + h3*s.C.w;
      p += __shfl_xor(p,1); p += __shfl_xor(p,2);
      p += __shfl_xor(p,4); p += __shfl_xor(p,8);
      if (sg == 0) {
        const float y = p + s.u*Dval;
        yp[(size_t)(base+TCH+t)*DI] = y * s.z * sigmoidf_(s.z);
      }
    }
  }
}

extern "C" void kernel_launch(void* const* d_in, const int* in_sizes, int n_in,
                              void* d_out, int out_size, void* d_ws, size_t ws_size,
                              hipStream_t stream)
{
  const float* x      = (const float*)d_in[0];
  const float* ln_w   = (const float*)d_in[1];
  const float* ln_b   = (const float*)d_in[2];
  const float* inpw   = (const float*)d_in[3];
  const float* convw  = (const float*)d_in[4];
  const float* convb  = (const float*)d_in[5];
  const float* xpw    = (const float*)d_in[6];
  const float* dtpw   = (const float*)d_in[7];
  const float* dtpb   = (const float*)d_in[8];
  const float* A_log  = (const float*)d_in[9];
  const float* Dmat   = (const float*)d_in[10];
  const float* outw   = (const float*)d_in[11];
  float* out = (float*)d_out;

  // Compact workspace layout with liveness-based aliasing (floats):
  //  R1 [8.4M]  : hln (ln -> in_proj), then xdb (x_proj -> scan)
  //  R2 [16.8M] : u_raw (in_proj -> conv), then dtb (dt -> scan),
  //               then y written in-place over dtb by scan (-> out_proj)
  //  R3 [16.8M] : zbuf (in_proj -> scan)
  //  R4 [16.8M] : ucb  (conv -> scan)
  // total = 58,720,256 floats = 224 MiB
  const size_t R1 = (size_t)NROWS * DM;          // 8,388,608
  const size_t RB = (size_t)NROWS * DI;          // 16,777,216
  const size_t need = (R1 + 3*RB) * sizeof(float);
  if (ws_size < need) {
    zero_kernel<<<(out_size+255)/256, 256, 0, stream>>>(out, out_size);
    return;
  }
  float* buf   = (float*)d_ws;
  float* hln   = buf;                 // R1
  float* xdb   = buf;                 // R1 (after hln dies)
  float* u_raw = buf + R1;            // R2
  float* dtb   = buf + R1;            // R2 (after u_raw dies); y in-place
  float* zbuf  = buf + R1 + RB;       // R3
  float* ucb   = buf + R1 + 2*RB;     // R4

  for (int l = 0; l < 2; ++l) {
    const float* xin = (l == 0) ? x : out;
    ln_kernel<<<NROWS/4, 256, 0, stream>>>(xin, ln_w + l*DM, ln_b + l*DM, hln);
    // in_proj split: u half and z half, each [NROWS x DI], K=DM
    gemm_bt<<<dim3(DI/BN, NROWS/BM), 256, 0, stream>>>(
        hln, inpw + (size_t)l*2*DI*DM, u_raw, nullptr, NROWS, DI, DM);
    gemm_bt<<<dim3(DI/BN, NROWS/BM), 256, 0, stream>>>(
        hln, inpw + (size_t)l*2*DI*DM + (size_t)DI*DM, zbuf, nullptr, NROWS, DI, DM);
    conv_silu_kernel<<<(NROWS*DI)/256, 256, 0, stream>>>(
        u_raw, convw + l*DI*4, convb + l*DI, ucb);
    gemm_bt<<<dim3((160+BN-1)/BN, NROWS/BM), 256, 0, stream>>>(
        ucb, xpw + (size_t)l*160*DI, xdb, nullptr, NROWS, 160, DI);
    dt_kernel<<<dim3(NROWS/64, DI/256), 256, 0, stream>>>(
        xdb, dtpw + (size_t)l*DI*DTR, dtpb + l*DI, dtb);
    scan_kernel<<<NB*64, 256, 0, stream>>>(
        dtb, ucb, zbuf, xdb, A_log + (size_t)l*DI*NDS, Dmat + l*DI, dtb /* y in-place */);
    gemm_bt<<<dim3(DM/BN, NROWS/BM), 256, 0, stream>>>(
        dtb, outw + (size_t)l*DM*DI, out, xin, NROWS, DM, DI);
  }
}

// Round 4
// 1921.353 us; speedup vs baseline: 2.0403x; 1.6569x over previous
//
#include <hip/hip_runtime.h>
#include <hip/hip_bf16.h>
#include <math.h>

// Problem constants (fixed by the reference)
#define NB   8
#define SL   2048
#define DM   512
#define DI   1024
#define NDS  64
#define DTR  32
#define NROWS (NB*SL)   // 16384

#define TCH 8   // scan time-chunk (register-resident, double-buffered)

typedef __attribute__((ext_vector_type(8))) short short8;
typedef __attribute__((ext_vector_type(4))) float f32x4;

__device__ __forceinline__ float sigmoidf_(float x){ return 1.0f/(1.0f + __expf(-x)); }

// ---------------- fallback: zero the output (ws too small diagnostic) -------
__global__ void __launch_bounds__(256) zero_kernel(float* __restrict__ p, int n)
{
  const int i = blockIdx.x*256 + threadIdx.x;
  if (i < n) p[i] = 0.0f;
}

// ---------------- f32 -> bf16 elementwise convert ----------------
__global__ void __launch_bounds__(256) cvt_bf16_kernel(const float* __restrict__ s,
    __hip_bfloat16* __restrict__ d, int n)
{
  const int i = blockIdx.x*256 + threadIdx.x;
  if (i < n) d[i] = __float2bfloat16(s[i]);
}

// ---------------- LayerNorm: one wave per row, bf16 output ----------------
__global__ void __launch_bounds__(256) ln_kernel(const float* __restrict__ x,
    const float* __restrict__ w, const float* __restrict__ b,
    __hip_bfloat16* __restrict__ out)
{
  const int wave = threadIdx.x >> 6;
  const int lane = threadIdx.x & 63;
  const int row  = (blockIdx.x << 2) + wave;
  const float* xr = x + (size_t)row * DM;
  float4 v0 = *(const float4*)(xr + lane*4);
  float4 v1 = *(const float4*)(xr + 256 + lane*4);
  float s = v0.x+v0.y+v0.z+v0.w + v1.x+v1.y+v1.z+v1.w;
  float q = v0.x*v0.x+v0.y*v0.y+v0.z*v0.z+v0.w*v0.w
          + v1.x*v1.x+v1.y*v1.y+v1.z*v1.z+v1.w*v1.w;
  #pragma unroll
  for (int off=1; off<64; off<<=1){ s += __shfl_xor(s, off); q += __shfl_xor(q, off); }
  const float mean = s * (1.0f/DM);
  const float var  = q * (1.0f/DM) - mean*mean;
  const float rstd = rsqrtf(var + 1e-5f);
  float4 w0 = *(const float4*)(w + lane*4);
  float4 w1 = *(const float4*)(w + 256 + lane*4);
  float4 b0 = *(const float4*)(b + lane*4);
  float4 b1 = *(const float4*)(b + 256 + lane*4);
  __hip_bfloat16* orow = out + (size_t)row * DM;
  orow[lane*4+0] = __float2bfloat16((v0.x-mean)*rstd*w0.x + b0.x);
  orow[lane*4+1] = __float2bfloat16((v0.y-mean)*rstd*w0.y + b0.y);
  orow[lane*4+2] = __float2bfloat16((v0.z-mean)*rstd*w0.z + b0.z);
  orow[lane*4+3] = __float2bfloat16((v0.w-mean)*rstd*w0.w + b0.w);
  orow[256+lane*4+0] = __float2bfloat16((v1.x-mean)*rstd*w1.x + b1.x);
  orow[256+lane*4+1] = __float2bfloat16((v1.y-mean)*rstd*w1.y + b1.y);
  orow[256+lane*4+2] = __float2bfloat16((v1.z-mean)*rstd*w1.z + b1.z);
  orow[256+lane*4+3] = __float2bfloat16((v1.w-mean)*rstd*w1.w + b1.w);
}

// ---------------- bf16 MFMA GEMM: C[M,N] = A[M,K] * W[N,K]^T (+res) --------
// 128x128 tile, BK=32, 4 waves, each wave 64x64 via 4x4 of 16x16x32 MFMA.
// A, W are bf16 (ushort bits), K-major. LDS rows padded to 40 ushorts (80 B):
// ds_read_b128 start-granule = (5*row+q) mod 8 -> every bank-residue exactly
// twice per wave = 2-way aliasing = free (m136). Register staging (m93-style);
// global_load_lds is incompatible with the pad.
// Fragment maps (guide §3, m89/m91-verified):
//   A/B operand: [m|n = lane&15][k = (lane>>4)*8 + j]
//   C/D:          col(n) = lane&15, row(m) = (lane>>4)*4 + reg
template<typename OutT, bool HasRes>
__global__ void __launch_bounds__(256) gemm_mfma(
    const ushort* __restrict__ A, const ushort* __restrict__ W,
    OutT* __restrict__ C, const float* __restrict__ res,
    int M, int N, int K)
{
  __shared__ __align__(16) ushort As[128*40];
  __shared__ __align__(16) ushort Ws[128*40];
  const int t    = threadIdx.x;
  const int m0   = blockIdx.y * 128;
  const int n0   = blockIdx.x * 128;
  const int lane = t & 63;
  const int wv   = t >> 6;
  const int wm   = wv >> 1, wn = wv & 1;
  const int fr   = lane & 15, fq = lane >> 4;

  // staging granules: g -> (row = g>>2, 16B-slab = g&3); thread covers g=t, t+256
  const int ar0 = t >> 2,        as0 = (t & 3) << 3;         // slab offset in ushorts
  const int ar1 = (t+256) >> 2,  as1 = as0;                  // (t+256)&3 == t&3
  const int wr0 = min(n0 + ar0, N-1);
  const int wr1 = min(n0 + ar1, N-1);

  f32x4 acc[4][4];
  #pragma unroll
  for (int i=0;i<4;i++)
    #pragma unroll
    for (int j=0;j<4;j++) acc[i][j] = (f32x4){0.f,0.f,0.f,0.f};

  const ushort* Ab = A + (size_t)m0 * K;

  for (int k0 = 0; k0 < K; k0 += 32) {
    const int4 av0 = *(const int4*)(Ab + (size_t)ar0*K + k0 + as0);
    const int4 av1 = *(const int4*)(Ab + (size_t)ar1*K + k0 + as1);
    const int4 wv0 = *(const int4*)(W  + (size_t)wr0*K + k0 + as0);
    const int4 wv1 = *(const int4*)(W  + (size_t)wr1*K + k0 + as1);
    *(int4*)&As[ar0*40 + as0] = av0;
    *(int4*)&As[ar1*40 + as1] = av1;
    *(int4*)&Ws[ar0*40 + as0] = wv0;
    *(int4*)&Ws[ar1*40 + as1] = wv1;
    __syncthreads();
    short8 af[4], wf[4];
    #pragma unroll
    for (int i=0;i<4;i++)
      af[i] = *(const short8*)&As[(wm*64 + i*16 + fr)*40 + fq*8];
    #pragma unroll
    for (int j=0;j<4;j++)
      wf[j] = *(const short8*)&Ws[(wn*64 + j*16 + fr)*40 + fq*8];
    #pragma unroll
    for (int i=0;i<4;i++)
      #pragma unroll
      for (int j=0;j<4;j++)
        acc[i][j] = __builtin_amdgcn_mfma_f32_16x16x32_bf16(af[i], wf[j], acc[i][j], 0, 0, 0);
    __syncthreads();
  }

  #pragma unroll
  for (int j=0;j<4;j++){
    const int n = n0 + wn*64 + j*16 + fr;
    if (n >= N) continue;
    #pragma unroll
    for (int i=0;i<4;i++){
      #pragma unroll
      for (int r=0;r<4;r++){
        const int m = m0 + wm*64 + i*16 + fq*4 + r;
        float v = acc[i][j][r];
        if (HasRes) v += res[(size_t)m*N + n];
        if (sizeof(OutT) == 2)
          ((__hip_bfloat16*)C)[(size_t)m*N + n] = __float2bfloat16(v);
        else
          ((float*)C)[(size_t)m*N + n] = v;
      }
    }
  }
}

// ---------------- Causal depthwise conv (width 4) + SiLU, bf16 in/out -------
__global__ void __launch_bounds__(256) conv_silu_kernel(
    const __hip_bfloat16* __restrict__ u_raw,
    const float* __restrict__ cw, const float* __restrict__ cb,
    __hip_bfloat16* __restrict__ uc)
{
  const int gid = blockIdx.x*256 + threadIdx.x;     // 0 .. NROWS*DI-1
  const int d   = gid & (DI-1);
  const int row = gid >> 10;
  const int l   = row & (SL-1);
  float acc = cb[d];
  const float* w = cw + d*4;
  #pragma unroll
  for (int k=0;k<4;k++){
    const int ll = l-3+k;
    if (ll >= 0) acc += __bfloat162float(u_raw[(size_t)(row-3+k)*DI + d]) * w[k];
  }
  const float s = acc * sigmoidf_(acc);
  uc[gid] = __float2bfloat16(s);
}

// ---------------- dt = softplus(dt_part @ dtp_w^T + b) ----------------
__global__ void __launch_bounds__(256) dt_kernel(const float* __restrict__ xdbl,
    const float* __restrict__ w, const float* __restrict__ bias, float* __restrict__ dt_out)
{
  const int d     = blockIdx.y*256 + threadIdx.x;
  const int rbase = blockIdx.x*64;
  float wr[32];
  #pragma unroll
  for (int i=0;i<8;i++){
    const float4 v = *(const float4*)(w + (size_t)d*DTR + i*4);
    wr[i*4+0]=v.x; wr[i*4+1]=v.y; wr[i*4+2]=v.z; wr[i*4+3]=v.w;
  }
  const float bb = bias[d];
  __shared__ __align__(16) float xd[64][32];
  #pragma unroll
  for (int ii=0; ii<2; ii++){
    const int i  = threadIdx.x + ii*256;   // 0..511 float4 slots
    const int rl = i >> 3, qo = (i & 7) << 2;
    const float4 v = *(const float4*)(xdbl + (size_t)(rbase+rl)*160 + qo);
    *(float4*)&xd[rl][qo] = v;
  }
  __syncthreads();
  for (int rl=0; rl<64; rl++){
    float acc = bb;
    #pragma unroll
    for (int r=0;r<DTR;r++) acc += xd[rl][r]*wr[r];
    const float sp = (acc > 20.0f) ? acc : logf(1.0f + __expf(acc));
    dt_out[(size_t)(rbase+rl)*DI + d] = sp;
  }
}

// ---------------- Selective scan (+ D skip + SiLU(z) gate) ----------------
// wave = (batch, 4 d-channels); lane: dl = lane>>4, sg = lane&15; 4 states/lane.
// Time in register-resident chunks of TCH with two buffers (MLP: ~40 loads in
// flight while computing the previous chunk from registers).
struct ScanStep { float dt, u, z; float4 B, C; };

__device__ __forceinline__ void scan_load_chunk(ScanStep s[TCH],
    const float* __restrict__ dtp, const __hip_bfloat16* __restrict__ up,
    const __hip_bfloat16* __restrict__ zp,
    const float* __restrict__ bp, const float* __restrict__ cp, int base)
{
  #pragma unroll
  for (int t=0; t<TCH; t++){
    const size_t o  = (size_t)(base+t)*DI;
    const size_t o2 = (size_t)(base+t)*160;
    s[t].dt = dtp[o];
    s[t].u  = __bfloat162float(up[o]);
    s[t].z  = __bfloat162float(zp[o]);
    s[t].B  = *(const float4*)(bp + o2);
    s[t].C  = *(const float4*)(cp + o2);
  }
}

__global__ void __launch_bounds__(256, 2) scan_kernel(
    const float* __restrict__ dt_s, const __hip_bfloat16* __restrict__ uc,
    const __hip_bfloat16* __restrict__ zb, const float* __restrict__ xdbl,
    const float* __restrict__ A_log, const float* __restrict__ Dv,
    __hip_bfloat16* __restrict__ yg)
{
  const int wave  = threadIdx.x >> 6;
  const int lane  = threadIdx.x & 63;
  const int batch = blockIdx.x >> 6;
  const int dbase = ((blockIdx.x & 63) << 4) + (wave << 2);
  const int dl = lane >> 4, sg = lane & 15;
  const int d  = dbase + dl;

  const float a0 = -__expf(A_log[(size_t)d*NDS + sg*4 + 0]);
  const float a1 = -__expf(A_log[(size_t)d*NDS + sg*4 + 1]);
  const float a2 = -__expf(A_log[(size_t)d*NDS + sg*4 + 2]);
  const float a3 = -__expf(A_log[(size_t)d*NDS + sg*4 + 3]);
  float h0=0.f,h1=0.f,h2=0.f,h3=0.f;
  const float Dval = Dv[d];

  const size_t r0 = (size_t)batch * SL;
  const float*          dtp = dt_s + r0*DI + d;
  const __hip_bfloat16* up  = uc   + r0*DI + d;
  const __hip_bfloat16* zp  = zb   + r0*DI + d;
  const float*          bp  = xdbl + r0*160 + 32 + (sg<<2);
  const float*          cp  = xdbl + r0*160 + 96 + (sg<<2);
  __hip_bfloat16*       yp  = yg   + r0*DI + d;

  ScanStep buf0[TCH], buf1[TCH];
  scan_load_chunk(buf0, dtp, up, zp, bp, cp, 0);

  for (int base = 0; base < SL; base += 2*TCH) {
    scan_load_chunk(buf1, dtp, up, zp, bp, cp, base + TCH);
    #pragma unroll
    for (int t=0; t<TCH; t++){
      const ScanStep& s = buf0[t];
      const float dtu = s.dt * s.u;
      h0 = __expf(s.dt*a0)*h0 + dtu*s.B.x;
      h1 = __expf(s.dt*a1)*h1 + dtu*s.B.y;
      h2 = __expf(s.dt*a2)*h2 + dtu*s.B.z;
      h3 = __expf(s.dt*a3)*h3 + dtu*s.B.w;
      float p = h0*s.C.x + h1*s.C.y + h2*s.C.z + h3*s.C.w;
      p += __shfl_xor(p,1); p += __shfl_xor(p,2);
      p += __shfl_xor(p,4); p += __shfl_xor(p,8);
      if (sg == 0) {
        const float y = p + s.u*Dval;
        yp[(size_t)(base+t)*DI] = __float2bfloat16(y * s.z * sigmoidf_(s.z));
      }
    }
    if (base + 2*TCH < SL)
      scan_load_chunk(buf0, dtp, up, zp, bp, cp, base + 2*TCH);
    #pragma unroll
    for (int t=0; t<TCH; t++){
      const ScanStep& s = buf1[t];
      const float dtu = s.dt * s.u;
      h0 = __expf(s.dt*a0)*h0 + dtu*s.B.x;
      h1 = __expf(s.dt*a1)*h1 + dtu*s.B.y;
      h2 = __expf(s.dt*a2)*h2 + dtu*s.B.z;
      h3 = __expf(s.dt*a3)*h3 + dtu*s.B.w;
      float p = h0*s.C.x + h1*s.C.y + h2*s.C.z + h3*s.C.w;
      p += __shfl_xor(p,1); p += __shfl_xor(p,2);
      p += __shfl_xor(p,4); p += __shfl_xor(p,8);
      if (sg == 0) {
        const float y = p + s.u*Dval;
        yp[(size_t)(base+TCH+t)*DI] = __float2bfloat16(y * s.z * sigmoidf_(s.z));
      }
    }
  }
}

extern "C" void kernel_launch(void* const* d_in, const int* in_sizes, int n_in,
                              void* d_out, int out_size, void* d_ws, size_t ws_size,
                              hipStream_t stream)
{
  const float* x      = (const float*)d_in[0];
  const float* ln_w   = (const float*)d_in[1];
  const float* ln_b   = (const float*)d_in[2];
  const float* inpw   = (const float*)d_in[3];
  const float* convw  = (const float*)d_in[4];
  const float* convb  = (const float*)d_in[5];
  const float* xpw    = (const float*)d_in[6];
  const float* dtpw   = (const float*)d_in[7];
  const float* dtpb   = (const float*)d_in[8];
  const float* A_log  = (const float*)d_in[9];
  const float* Dmat   = (const float*)d_in[10];
  const float* outw   = (const float*)d_in[11];
  float* out = (float*)d_out;

  // Workspace layout (bf16 intermediates; ~190 MiB < 224 MiB known-good):
  //  R1: hln_bf16    [NROWS*DM]  16 MB  (ln -> in_proj)
  //  R2: u_raw_bf16  [NROWS*DI]  32 MB  (in_proj -> conv), then y_bf16 (scan -> out_proj)
  //  R3: z_bf16      [NROWS*DI]  32 MB  (in_proj -> scan)
  //  R4: uc_bf16     [NROWS*DI]  32 MB  (conv -> x_proj, scan)
  //  R5: xdb f32     [NROWS*160] 10 MB  (x_proj -> dt, scan B/C)
  //  R6: dtb f32     [NROWS*DI]  64 MB  (dt -> scan)
  //  R7: weight bf16 scratch      3.3 MB (per-layer converted)
  const size_t nIn   = (size_t)2*DI*DM;    // in_proj_w elements per layer
  const size_t nXp   = (size_t)160*DI;
  const size_t nOutW = (size_t)DM*DI;
  size_t off = 0;
  char* base = (char*)d_ws;
  auto alloc = [&](size_t bytes)->char*{ char* p = base + off; off += (bytes + 255) & ~(size_t)255; return p; };
  __hip_bfloat16* hln   = (__hip_bfloat16*)alloc((size_t)NROWS*DM*2);
  __hip_bfloat16* ubf   = (__hip_bfloat16*)alloc((size_t)NROWS*DI*2);  // u_raw, then y
  __hip_bfloat16* zbf   = (__hip_bfloat16*)alloc((size_t)NROWS*DI*2);
  __hip_bfloat16* ucb   = (__hip_bfloat16*)alloc((size_t)NROWS*DI*2);
  float*          xdb   = (float*)alloc((size_t)NROWS*160*4);
  float*          dtb   = (float*)alloc((size_t)NROWS*DI*4);
  __hip_bfloat16* wIn   = (__hip_bfloat16*)alloc(nIn*2);
  __hip_bfloat16* wXp   = (__hip_bfloat16*)alloc(nXp*2);
  __hip_bfloat16* wOut  = (__hip_bfloat16*)alloc(nOutW*2);
  if (ws_size < off) {
    zero_kernel<<<(out_size+255)/256, 256, 0, stream>>>(out, out_size);
    return;
  }

  for (int l = 0; l < 2; ++l) {
    const float* xin = (l == 0) ? x : out;
    // per-layer weight conversion f32 -> bf16 (cheap, memory-bound)
    cvt_bf16_kernel<<<(int)((nIn  +255)/256), 256, 0, stream>>>(inpw + (size_t)l*nIn,  wIn,  (int)nIn);
    cvt_bf16_kernel<<<(int)((nXp  +255)/256), 256, 0, stream>>>(xpw  + (size_t)l*nXp,  wXp,  (int)nXp);
    cvt_bf16_kernel<<<(int)((nOutW+255)/256), 256, 0, stream>>>(outw + (size_t)l*nOutW, wOut, (int)nOutW);

    ln_kernel<<<NROWS/4, 256, 0, stream>>>(xin, ln_w + l*DM, ln_b + l*DM, hln);

    // in_proj: u half and z half, each [NROWS x DI], K=DM, bf16 out
    gemm_mfma<__hip_bfloat16,false><<<dim3(DI/128, NROWS/128), 256, 0, stream>>>(
        (const ushort*)hln, (const ushort*)wIn, ubf, nullptr, NROWS, DI, DM);
    gemm_mfma<__hip_bfloat16,false><<<dim3(DI/128, NROWS/128), 256, 0, stream>>>(
        (const ushort*)hln, (const ushort*)(wIn + (size_t)DI*DM), zbf, nullptr, NROWS, DI, DM);

    conv_silu_kernel<<<(NROWS*DI)/256, 256, 0, stream>>>(
        ubf, convw + l*DI*4, convb + l*DI, ucb);

    // x_proj: [NROWS x 160], K=DI, f32 out (N=160 -> 2 N-tiles, bounds-checked)
    gemm_mfma<float,false><<<dim3(2, NROWS/128), 256, 0, stream>>>(
        (const ushort*)ucb, (const ushort*)wXp, xdb, nullptr, NROWS, 160, DI);

    dt_kernel<<<dim3(NROWS/64, DI/256), 256, 0, stream>>>(
        xdb, dtpw + (size_t)l*DI*DTR, dtpb + l*DI, dtb);

    // scan writes y (bf16) into R2 (u_raw dead after conv)
    scan_kernel<<<NB*64, 256, 0, stream>>>(
        dtb, ucb, zbf, xdb, A_log + (size_t)l*DI*NDS, Dmat + l*DI, ubf);

    // out_proj: [NROWS x DM], K=DI, f32 out + residual
    gemm_mfma<float,true><<<dim3(DM/128, NROWS/128), 256, 0, stream>>>(
        (const ushort*)ubf, (const ushort*)wOut, out, xin, NROWS, DM, DI);
  }
}